// Round 5
// baseline (240.316 us; speedup 1.0000x reference)
//
#include <hip/hip_runtime.h>
#include <hip/hip_bf16.h>

// QuantumLayer: 8-qubit circuit, batch 65536.
// Math: final = V * m  with V = U(weights) * diag((-i)^popc(j)) complex 256x256,
//       m[b][j] = prod_q (bit_q(j) ? sin(x_bq/2) : cos(x_bq/2))  (real).
// W (fp16): W[i][j]=Re V[i][j], W[i+256][j]=Im V[i][j] -> 512x256 [r][k].
// out[b][q] = sum_i sign_q(i) * (C[b][i]^2 + C[b][i+256]^2),  C = m * W^T (fp16 MFMA).
//
// SINGLE plain dispatch, 256 blocks x 256 threads (all co-resident: 64KB LDS
// -> >=1 block/CU on 256 CUs). Phase 1: block b builds W column b. Custom
// sense-reversing grid barrier (device-scope atomics). Phase 2: each block
// does the GEMM+epilogue for 256 samples (8 groups of 32).

typedef __attribute__((ext_vector_type(8))) short short8;
typedef __attribute__((ext_vector_type(8))) _Float16 half8;
typedef __attribute__((ext_vector_type(4))) float f32x4;

// W: rewritten every call from wt only (call-invariant values).
__device__ _Float16 g_W[512 * 256];
// Grid barrier state. Self-cleaning: ctr returns to 0 each call; sense flips
// each call but behavior/values are identical regardless of its value.
__device__ int g_ctr = 0;
__device__ int g_sense = 0;

#define NBLK 256

__global__ __launch_bounds__(256) void fused(const float* __restrict__ x,
                                             const float* __restrict__ wt,
                                             float* __restrict__ out) {
    __shared__ __align__(16) char smem[65536];
    const int tid = threadIdx.x;
    const int bid = blockIdx.x;

    // ---------------- phase 1: block `bid` builds column `bid` of V ----------
    {
        float2* amp = (float2*)smem;   // 2 KB
        const int col = bid;
        amp[tid] = make_float2(tid == col ? 1.f : 0.f, 0.f);
        __syncthreads();

        for (int lyr = 0; lyr < 8; ++lyr) {
            // RY(w[l][q][0]) then RZ(w[l][q][1]) on wire q (wire 0 = MSB)
            for (int q = 0; q < 8; ++q) {
                float ty = 0.5f * wt[(lyr * 8 + q) * 2 + 0];
                float tz = 0.5f * wt[(lyr * 8 + q) * 2 + 1];
                float cy = cosf(ty), sy = sinf(ty);
                float ezr = cosf(tz), ezi = sinf(tz);
                int mask = 1 << (7 - q);
                float2 a = amp[tid];
                float2 b = amp[tid ^ mask];
                bool hi = (tid & mask) != 0;
                float tr = cy * a.x + (hi ? sy * b.x : -sy * b.x);
                float ti = cy * a.y + (hi ? sy * b.y : -sy * b.y);
                float pi = hi ? ezi : -ezi;
                float2 nv = make_float2(tr * ezr - ti * pi, tr * pi + ti * ezr);
                __syncthreads();
                amp[tid] = nv;
                __syncthreads();
            }
            // CNOT(q, (q+1)%8)
            for (int q = 0; q < 8; ++q) {
                int cm = 1 << (7 - q);
                int tm = 1 << (7 - ((q + 1) & 7));
                int src = (tid & cm) ? (tid ^ tm) : tid;
                float2 nv = amp[src];
                __syncthreads();
                amp[tid] = nv;
                __syncthreads();
            }
        }

        // fold column phase p = (-i)^popcount(col), store fp16 W
        int pc = __popc(col) & 3;
        float pr = (pc == 0) ? 1.f : (pc == 2) ? -1.f : 0.f;
        float pim = (pc == 1) ? -1.f : (pc == 3) ? 1.f : 0.f;
        float2 a = amp[tid];
        g_W[tid * 256 + col] = (_Float16)(a.x * pr - a.y * pim);
        g_W[(tid + 256) * 256 + col] = (_Float16)(a.x * pim + a.y * pr);
    }

    // ---------------- grid barrier (sense-reversing, device scope) ----------
    __syncthreads();                 // all of this block's g_W writes issued
    if (tid == 0) {
        __threadfence();             // release g_W writes to device scope
        int my_sense = __hip_atomic_load(&g_sense, __ATOMIC_RELAXED,
                                         __HIP_MEMORY_SCOPE_AGENT) ^ 1;
        int arrived = __hip_atomic_fetch_add(&g_ctr, 1, __ATOMIC_ACQ_REL,
                                             __HIP_MEMORY_SCOPE_AGENT) + 1;
        if (arrived == NBLK) {
            __hip_atomic_store(&g_ctr, 0, __ATOMIC_RELAXED,
                               __HIP_MEMORY_SCOPE_AGENT);
            __hip_atomic_store(&g_sense, my_sense, __ATOMIC_RELEASE,
                               __HIP_MEMORY_SCOPE_AGENT);
        } else {
            while (__hip_atomic_load(&g_sense, __ATOMIC_ACQUIRE,
                                     __HIP_MEMORY_SCOPE_AGENT) != my_sense) {}
        }
        __threadfence();             // acquire: order subsequent g_W reads
    }
    __syncthreads();

    // ---------------- phase 2: GEMM + epilogue, 8 groups of 32 samples ------
    const int wv = tid >> 6;      // wave 0..3
    const int l = tid & 63;
    const int c = l & 15;         // A row / B col / D col lane index
    const int g = l >> 4;         // k-group 0..3
    const _Float16* Wg = g_W;

    for (int grp = 0; grp < 8; ++grp) {
        const int sb = bid * 256 + grp * 32;

        // ---- A fragments: m[sample][k] in fp16 registers ----
        // A lane layout (16x16x32): row = lane&15, k = (lane>>4)*8 + e
        half8 afrag[2][8];
        for (int sg = 0; sg < 2; ++sg) {
            const int s = sb + sg * 16 + c;
            float cc[8], ss[8];
#pragma unroll
            for (int q = 0; q < 8; ++q) {
                float xv = 0.5f * x[s * 8 + q];
                cc[q] = cosf(xv);
                ss[q] = sinf(xv);
            }
            // k bits: [7:5]=step (wires 0..2), [4:3]=g (wires 3,4), [2:0]=e (wires 5..7)
            float A[8], Dv[8];
#pragma unroll
            for (int t = 0; t < 8; ++t)
                A[t] = ((t & 4) ? ss[0] : cc[0]) * ((t & 2) ? ss[1] : cc[1]) * ((t & 1) ? ss[2] : cc[2]);
            const float Bf = ((g & 2) ? ss[3] : cc[3]) * ((g & 1) ? ss[4] : cc[4]);
#pragma unroll
            for (int u = 0; u < 8; ++u)
                Dv[u] = Bf * ((u & 4) ? ss[5] : cc[5]) * ((u & 2) ? ss[6] : cc[6]) * ((u & 1) ? ss[7] : cc[7]);
#pragma unroll
            for (int step = 0; step < 8; ++step) {
                half8 fr;
#pragma unroll
                for (int e = 0; e < 8; ++e)
                    fr[e] = (_Float16)(A[step] * Dv[e]);
                afrag[sg][step] = fr;
            }
        }

        f32x4 acc[2][8];
#pragma unroll
        for (int sg = 0; sg < 2; ++sg)
#pragma unroll
            for (int f = 0; f < 8; ++f)
                acc[sg][f] = (f32x4){0.f, 0.f, 0.f, 0.f};

        // ---- K loop: 4 chunks of 64 ----
        for (int kc = 0; kc < 4; ++kc) {
            __syncthreads();   // protect previous chunk's (or prev grp's) reads
            // stage [512][64] fp16, swizzled: byte = (row*128 + kl*2) ^ ((row&7)<<4)
#pragma unroll
            for (int it = 0; it < 16; ++it) {
                int t = tid + it * 256;
                int row = t >> 3;
                int kb = (t & 7) * 8;
                short8 v = *(const short8*)((const short*)Wg + row * 256 + kc * 64 + kb);
                int byte = (row * 128 + kb * 2) ^ ((row & 7) << 4);
                *(short8*)(smem + byte) = v;
            }
            __syncthreads();
#pragma unroll
            for (int st = 0; st < 2; ++st) {
#pragma unroll
                for (int f = 0; f < 8; ++f) {
                    int r = wv * 128 + f * 16 + c;
                    int kl = st * 32 + g * 8;
                    int byte = (r * 128 + kl * 2) ^ ((r & 7) << 4);
                    half8 b = *(const half8*)(smem + byte);
                    acc[0][f] = __builtin_amdgcn_mfma_f32_16x16x32_f16(afrag[0][kc * 2 + st], b, acc[0][f], 0, 0, 0);
                    acc[1][f] = __builtin_amdgcn_mfma_f32_16x16x32_f16(afrag[1][kc * 2 + st], b, acc[1][f], 0, 0, 0);
                }
            }
        }

        // ---- epilogue: C through LDS (swizzled), probs, signed reduce ----
        __syncthreads();       // all MFMA LDS reads done before overwriting smem
        float* Cs = (float*)smem;
        // D layout: col = lane&15 (row r), row = (lane>>4)*4 + j (sample in group)
#pragma unroll
        for (int sg = 0; sg < 2; ++sg)
#pragma unroll
            for (int f = 0; f < 8; ++f) {
                int r = wv * 128 + f * 16 + c;
#pragma unroll
                for (int j = 0; j < 4; ++j) {
                    int s = sg * 16 + g * 4 + j;
                    Cs[r * 32 + (s ^ (r & 31))] = acc[sg][f][j];
                }
            }
        __syncthreads();

        const int s2 = tid >> 3;   // sample 0..31
        const int seg = tid & 7;   // i-segment
        float part[8] = {0.f, 0.f, 0.f, 0.f, 0.f, 0.f, 0.f, 0.f};
#pragma unroll
        for (int ii = 0; ii < 32; ++ii) {
            int ilo = (ii + seg * 4) & 31;       // rotate per seg to spread banks
            int i = seg * 32 + ilo;
            float fr = Cs[i * 32 + (s2 ^ ilo)];
            float fi = Cs[(i + 256) * 32 + (s2 ^ ilo)];
            float p = fr * fr + fi * fi;
#pragma unroll
            for (int q = 0; q < 8; ++q)
                part[q] += ((i >> (7 - q)) & 1) ? -p : p;
        }
#pragma unroll
        for (int m = 1; m < 8; m <<= 1)
#pragma unroll
            for (int q = 0; q < 8; ++q)
                part[q] += __shfl_xor(part[q], m, 64);
        out[(sb + s2) * 8 + seg] = part[seg];

        __syncthreads();   // smem reuse guard before next group's staging
    }
}

extern "C" void kernel_launch(void* const* d_in, const int* in_sizes, int n_in,
                              void* d_out, int out_size, void* d_ws, size_t ws_size,
                              hipStream_t stream) {
    const float* x = (const float*)d_in[0];       // (65536, 8) f32
    const float* wt = (const float*)d_in[1];      // (8, 8, 2) f32
    float* out = (float*)d_out;                   // (65536, 8) f32
    (void)d_ws; (void)ws_size; (void)in_sizes; (void)n_in; (void)out_size;

    fused<<<NBLK, 256, 0, stream>>>(x, wt, out);
}

// Round 6
// 103.640 us; speedup vs baseline: 2.3187x; 2.3187x over previous
//
#include <hip/hip_runtime.h>
#include <hip/hip_bf16.h>

// QuantumLayer: 8-qubit circuit, batch 65536.
// final = V*m; V = U(weights)*diag((-i)^popc(j)); m[b][j] = prod_q (bit? sin:cos)(x/2).
// W (fp16): [Re V; Im V] 512x256 row-major [r][k], built in-kernel.
// C = m * W^T via 16x16x32 fp16 MFMA, B-operand held in REGISTERS (no LDS staging).
// out[b][q] = sum_i sign_q(i) * (C_re[i]^2 + C_im[i]^2).
//
// One dispatch: 256 blocks x 512 threads (8 waves, 2/SIMD). Phase 1: wave 0
// builds column bid in registers via shfl (0 barriers). Grid barrier (validated
// r5 pattern). Phase 2: 8 groups of 32 samples; per wave 64 W-rows in 128 VGPR;
// epilogue = in-lane Re/Im pairing + signed vector-halving shuffle reduce.

typedef __attribute__((ext_vector_type(8))) _Float16 half8;
typedef __attribute__((ext_vector_type(4))) float f32x4;

__device__ _Float16 g_W[512 * 256];
// Grid barrier state (self-cleaning; validated in round 5).
__device__ int g_ctr = 0;
__device__ int g_sense = 0;

#define NBLK 256

__global__ __launch_bounds__(512, 2) void fused(const float* __restrict__ x,
                                                const float* __restrict__ wt,
                                                float* __restrict__ out) {
    __shared__ float part[8][32][8];   // [wave][sample-in-group][q] partials, 8KB
    const int tid = threadIdx.x;
    const int bid = blockIdx.x;
    const int wv = tid >> 6;
    const int lane = tid & 63;
    const int c = lane & 15;
    const int g4 = lane >> 4;

    // ---------------- phase 1: wave 0 builds column `bid` (regs + shfl) -----
    if (wv == 0) {
        float2 a[4];   // amps i = u*64 + lane
#pragma unroll
        for (int u = 0; u < 4; ++u)
            a[u] = make_float2((u * 64 + lane) == bid ? 1.f : 0.f, 0.f);

        for (int lyr = 0; lyr < 8; ++lyr) {
            // RY then RZ on wire q (wire 0 = MSB)
#pragma unroll
            for (int q = 0; q < 8; ++q) {
                const int mask = 1 << (7 - q);
                float ty = 0.5f * wt[(lyr * 8 + q) * 2 + 0];
                float tz = 0.5f * wt[(lyr * 8 + q) * 2 + 1];
                float cy = __cosf(ty), sy = __sinf(ty);
                float ezr = __cosf(tz), ezi = __sinf(tz);
                float2 b[4];
                bool hi[4];
                if (mask == 128) {
                    b[0] = a[2]; b[1] = a[3]; b[2] = a[0]; b[3] = a[1];
                    hi[0] = false; hi[1] = false; hi[2] = true; hi[3] = true;
                } else if (mask == 64) {
                    b[0] = a[1]; b[1] = a[0]; b[2] = a[3]; b[3] = a[2];
                    hi[0] = false; hi[1] = true; hi[2] = false; hi[3] = true;
                } else {
#pragma unroll
                    for (int u = 0; u < 4; ++u) {
                        b[u].x = __shfl_xor(a[u].x, mask, 64);
                        b[u].y = __shfl_xor(a[u].y, mask, 64);
                        hi[u] = (lane & mask) != 0;
                    }
                }
#pragma unroll
                for (int u = 0; u < 4; ++u) {
                    float sgn = hi[u] ? sy : -sy;
                    float tr = cy * a[u].x + sgn * b[u].x;
                    float ti = cy * a[u].y + sgn * b[u].y;
                    float pi = hi[u] ? ezi : -ezi;
                    a[u] = make_float2(tr * ezr - ti * pi, tr * pi + ti * ezr);
                }
            }
            // CNOT(q, (q+1)%8)
#pragma unroll
            for (int q = 0; q < 8; ++q) {
                const int cm = 1 << (7 - q);
                const int tm = 1 << (7 - ((q + 1) & 7));
                float2 b[4];
#pragma unroll
                for (int u = 0; u < 4; ++u) {
                    if (tm == 128) b[u] = a[u ^ 2];
                    else if (tm == 64) b[u] = a[u ^ 1];
                    else {
                        b[u].x = __shfl_xor(a[u].x, tm, 64);
                        b[u].y = __shfl_xor(a[u].y, tm, 64);
                    }
                }
#pragma unroll
                for (int u = 0; u < 4; ++u) {
                    int i = u * 64 + lane;
                    a[u] = (i & cm) ? b[u] : a[u];
                }
            }
        }
        // fold column phase (-i)^popc(bid); write fp16 W
        int pc = __popc(bid) & 3;
        float pr = (pc == 0) ? 1.f : (pc == 2) ? -1.f : 0.f;
        float pim = (pc == 1) ? -1.f : (pc == 3) ? 1.f : 0.f;
#pragma unroll
        for (int u = 0; u < 4; ++u) {
            int i = u * 64 + lane;
            g_W[i * 256 + bid] = (_Float16)(a[u].x * pr - a[u].y * pim);
            g_W[(i + 256) * 256 + bid] = (_Float16)(a[u].x * pim + a[u].y * pr);
        }
    }

    // ---------------- grid barrier (sense-reversing, validated r5) ----------
    __syncthreads();
    if (tid == 0) {
        __threadfence();
        int my_sense = __hip_atomic_load(&g_sense, __ATOMIC_RELAXED,
                                         __HIP_MEMORY_SCOPE_AGENT) ^ 1;
        int arrived = __hip_atomic_fetch_add(&g_ctr, 1, __ATOMIC_ACQ_REL,
                                             __HIP_MEMORY_SCOPE_AGENT) + 1;
        if (arrived == NBLK) {
            __hip_atomic_store(&g_ctr, 0, __ATOMIC_RELAXED,
                               __HIP_MEMORY_SCOPE_AGENT);
            __hip_atomic_store(&g_sense, my_sense, __ATOMIC_RELEASE,
                               __HIP_MEMORY_SCOPE_AGENT);
        } else {
            while (__hip_atomic_load(&g_sense, __ATOMIC_ACQUIRE,
                                     __HIP_MEMORY_SCOPE_AGENT) != my_sense) {}
        }
        __threadfence();
    }
    __syncthreads();

    // ---------------- B-operand: 64 W-rows per wave in registers ------------
    // f=0,1: Re rows wv*32+f*16+c ; f=2,3: Im rows 256 + wv*32 + (f-2)*16 + c.
    // B-frag lane layout (validated): col = lane&15, k = (lane>>4)*8 + e.
    half8 bfr[4][8];
#pragma unroll
    for (int f = 0; f < 4; ++f) {
        int row = (f >> 1) * 256 + wv * 32 + (f & 1) * 16 + c;
#pragma unroll
        for (int st = 0; st < 8; ++st)
            bfr[f][st] = *(const half8*)&g_W[row * 256 + st * 32 + g4 * 8];
    }

    // ---------------- main loop: 8 groups of 32 samples ---------------------
    for (int grp = 0; grp < 8; ++grp) {
        const int sb = bid * 256 + grp * 32;

        f32x4 acc[2][4];
#pragma unroll
        for (int sg = 0; sg < 2; ++sg)
#pragma unroll
            for (int f = 0; f < 4; ++f)
                acc[sg][f] = (f32x4){0.f, 0.f, 0.f, 0.f};

#pragma unroll
        for (int sg = 0; sg < 2; ++sg) {
            const int s = sb + sg * 16 + c;
            float cc[8], ss[8];
#pragma unroll
            for (int q = 0; q < 8; ++q) {
                float xv = 0.5f * x[s * 8 + q];
                cc[q] = __cosf(xv);
                ss[q] = __sinf(xv);
            }
            // k bits: [7:5]=st (wires 0-2), [4:3]=g4 (wires 3-4), [2:0]=e (wires 5-7)
            float A[8], Dv[8];
#pragma unroll
            for (int t = 0; t < 8; ++t)
                A[t] = ((t & 4) ? ss[0] : cc[0]) * ((t & 2) ? ss[1] : cc[1]) * ((t & 1) ? ss[2] : cc[2]);
            const float Bf = ((g4 & 2) ? ss[3] : cc[3]) * ((g4 & 1) ? ss[4] : cc[4]);
#pragma unroll
            for (int u = 0; u < 8; ++u)
                Dv[u] = Bf * ((u & 4) ? ss[5] : cc[5]) * ((u & 2) ? ss[6] : cc[6]) * ((u & 1) ? ss[7] : cc[7]);
#pragma unroll
            for (int st = 0; st < 8; ++st) {
                half8 fr;
#pragma unroll
                for (int e = 0; e < 8; ++e)
                    fr[e] = (_Float16)(A[st] * Dv[e]);
#pragma unroll
                for (int f = 0; f < 4; ++f)
                    acc[sg][f] = __builtin_amdgcn_mfma_f32_16x16x32_f16(fr, bfr[f][st], acc[sg][f], 0, 0, 0);
            }
        }

        // ---- epilogue: in-lane Re/Im pairing + signed shuffle reduction ----
        // D layout (validated): col = lane&15 -> r-offset c; row = g4*4+j -> sample.
        // i = wv*32 + f01*16 + c; q<->bit(7-q): q0..2 <- wv, q3 <- f01, q4..7 <- c.
#pragma unroll
        for (int sg = 0; sg < 2; ++sg) {
#pragma unroll
            for (int j = 0; j < 4; ++j) {
                float p0 = acc[sg][0][j] * acc[sg][0][j] + acc[sg][2][j] * acc[sg][2][j];
                float p1 = acc[sg][1][j] * acc[sg][1][j] + acc[sg][3][j] * acc[sg][3][j];
                float S = p0 + p1, Dd = p0 - p1;
                int iq = wv * 32 + c;
                float v[8];
#pragma unroll
                for (int q = 0; q < 8; ++q)
                    v[q] = (q == 3) ? Dd : (((iq >> (7 - q)) & 1) ? -S : S);
                // vector-halving sum over the 16 c-lanes
                float t[4];
#pragma unroll
                for (int z = 0; z < 4; ++z) {
                    float keep = (c & 1) ? v[4 + z] : v[z];
                    float send = (c & 1) ? v[z] : v[4 + z];
                    t[z] = keep + __shfl_xor(send, 1, 64);
                }
                float u2[2];
#pragma unroll
                for (int z = 0; z < 2; ++z) {
                    float keep = (c & 2) ? t[2 + z] : t[z];
                    float send = (c & 2) ? t[z] : t[2 + z];
                    u2[z] = keep + __shfl_xor(send, 2, 64);
                }
                float keep = (c & 4) ? u2[1] : u2[0];
                float send = (c & 4) ? u2[0] : u2[1];
                float w1 = keep + __shfl_xor(send, 4, 64);
                w1 += __shfl_xor(w1, 8, 64);
                if (c < 8) {
                    int qq = (c & 1) * 4 + ((c >> 1) & 1) * 2 + ((c >> 2) & 1);
                    part[wv][sg * 16 + g4 * 4 + j][qq] = w1;
                }
            }
        }
        __syncthreads();
        if (tid < 256) {
            int s = tid >> 3, q = tid & 7;
            float sum = 0.f;
#pragma unroll
            for (int w = 0; w < 8; ++w) sum += part[w][s][q];
            out[(sb + s) * 8 + q] = sum;
        }
        __syncthreads();
    }
}

extern "C" void kernel_launch(void* const* d_in, const int* in_sizes, int n_in,
                              void* d_out, int out_size, void* d_ws, size_t ws_size,
                              hipStream_t stream) {
    const float* x = (const float*)d_in[0];       // (65536, 8) f32
    const float* wt = (const float*)d_in[1];      // (8, 8, 2) f32
    float* out = (float*)d_out;                   // (65536, 8) f32
    (void)d_ws; (void)ws_size; (void)in_sizes; (void)n_in; (void)out_size;

    fused<<<NBLK, 512, 0, stream>>>(x, wt, out);
}